// Round 1
// 995.103 us; speedup vs baseline: 1.0106x; 1.0106x over previous
//
#include <hip/hip_runtime.h>
#include <hip/hip_bf16.h>

// CrossAttention: B=16, Lq=Lk=2048, Dq=768, Dk=1024, fp32 in/out.
// 256x256 tile, BK=32, 8 waves (2x4), 16x16x32 bf16 MFMA.
// Phase-scheduled pipeline (T2+T3+T4+T5):
//   - 4-deep LDS buffer rotation (128 KiB), stage tile t+3 during tile t
//   - counted s_waitcnt vmcnt(8) once per K-tile (never 0 in main loop)
//   - raw s_barrier + manual lgkmcnt(0); 16 MFMA per phase, setprio around MFMA
//   - XOR-swizzled staging (inverse-swizzled global source, swizzled ds_read)
// Pipeline: q = qa@WqT^T+bq ; k = ka@WkT^T+bk ; vT = WvT@ka^T+bv (per-batch)
//           P = exp(q k^T/32) bf16 + fp32 row_sum ; out = (P@vT^T)/row_sum

typedef __attribute__((ext_vector_type(4))) float  f32x4;
typedef __attribute__((ext_vector_type(8))) __bf16 bf16x8;

#define BM 256
#define BN 256
#define BK 32

__device__ __forceinline__ void gload_lds16(const __bf16* g, __bf16* l) {
    __builtin_amdgcn_global_load_lds(
        (const __attribute__((address_space(1))) void*)g,
        (__attribute__((address_space(3))) void*)l, 16, 0, 0);
}

enum { MODE_PROJ = 0, MODE_PROJT = 1, MODE_SCORE = 2, MODE_PV = 3 };

// 16 MFMAs of one m-row against b0..b3
#define MF(m_, a_)                                                              \
    acc[m_][0] = __builtin_amdgcn_mfma_f32_16x16x32_bf16(a_, b0, acc[m_][0], 0, 0, 0); \
    acc[m_][1] = __builtin_amdgcn_mfma_f32_16x16x32_bf16(a_, b1, acc[m_][1], 0, 0, 0); \
    acc[m_][2] = __builtin_amdgcn_mfma_f32_16x16x32_bf16(a_, b2, acc[m_][2], 0, 0, 0); \
    acc[m_][3] = __builtin_amdgcn_mfma_f32_16x16x32_bf16(a_, b3, acc[m_][3], 0, 0, 0);

// One K-tile = 2 phases x 16 MFMA. B_ = buffer to compute from, NB_ = buffer
// to stage tile t+3 into. VM_WAIT = counted vmcnt guaranteeing tile t+1 ready.
#define TILE_STEP(B_, NB_, DO_STAGE, VM_WAIT) do {                              \
    const __bf16* __restrict__ Ab = As[B_];                                     \
    const __bf16* __restrict__ Bb = Bs[B_];                                     \
    bf16x8 a0, a1, a2, a3, a4, a5, a6, a7, b0, b1, b2, b3;                      \
    /* ---- phase 1: reads + A-stage ---- */                                    \
    a0 = *(const bf16x8*)&Ab[raA];                                              \
    a1 = *(const bf16x8*)&Ab[raA + 512];                                        \
    a2 = *(const bf16x8*)&Ab[raA + 1024];                                       \
    a3 = *(const bf16x8*)&Ab[raA + 1536];                                       \
    b0 = *(const bf16x8*)&Bb[raB];                                              \
    b1 = *(const bf16x8*)&Bb[raB + 512];                                        \
    b2 = *(const bf16x8*)&Bb[raB + 1024];                                       \
    b3 = *(const bf16x8*)&Bb[raB + 1536];                                       \
    if (DO_STAGE) {                                                             \
        gload_lds16(ap0, &As[NB_][wA]);                                         \
        gload_lds16(ap1, &As[NB_][wA + 512]);                                   \
        ap0 += BK; ap1 += BK;                                                   \
    }                                                                           \
    asm volatile("" ::: "memory");                                              \
    __builtin_amdgcn_s_barrier();                                               \
    asm volatile("s_waitcnt lgkmcnt(0)" ::: "memory");                          \
    __builtin_amdgcn_s_setprio(1);                                              \
    MF(0, a0) MF(1, a1) MF(2, a2) MF(3, a3)                                     \
    __builtin_amdgcn_s_setprio(0);                                              \
    asm volatile("" ::: "memory");                                              \
    __builtin_amdgcn_s_barrier();                                               \
    /* ---- phase 2: reads + B-stage + counted vmcnt ---- */                    \
    a4 = *(const bf16x8*)&Ab[raA + 2048];                                       \
    a5 = *(const bf16x8*)&Ab[raA + 2560];                                       \
    a6 = *(const bf16x8*)&Ab[raA + 3072];                                       \
    a7 = *(const bf16x8*)&Ab[raA + 3584];                                       \
    if (DO_STAGE) {                                                             \
        gload_lds16(bp0, &Bs[NB_][wA]);                                         \
        gload_lds16(bp1, &Bs[NB_][wA + 512]);                                   \
        bp0 += BK; bp1 += BK;                                                   \
    }                                                                           \
    VM_WAIT;                                                                    \
    asm volatile("" ::: "memory");                                              \
    __builtin_amdgcn_s_barrier();                                               \
    asm volatile("s_waitcnt lgkmcnt(0)" ::: "memory");                          \
    __builtin_amdgcn_s_setprio(1);                                              \
    MF(4, a4) MF(5, a5) MF(6, a6) MF(7, a7)                                     \
    __builtin_amdgcn_s_setprio(0);                                              \
    asm volatile("" ::: "memory");                                              \
    __builtin_amdgcn_s_barrier();                                               \
} while (0)

// ---------------------------------------------------------------------------
// Unified 256x256 NT GEMM: C[m][n] = sum_k A[m][k] * B[n][k]  (+ epilogue)
// ---------------------------------------------------------------------------
template <int MODE>
__global__ __launch_bounds__(512, 2) void gemm256(
    const __bf16* __restrict__ Ag, const __bf16* __restrict__ Bg,
    const float* __restrict__ aux,   // bias (PROJ: per-col, PROJT: per-row)
    float* __restrict__ rs,          // row_sum (SCORE: atomic out, PV: in)
    void* __restrict__ Cg,
    int K, int lda, int ldb, int ldc,
    long batchA, long batchB, long batchC, long batchRS)
{
    __shared__ __bf16 As[4][BM * BK];   // 4 x 16 KiB
    __shared__ __bf16 Bs[4][BN * BK];   // 4 x 16 KiB
    const int t    = threadIdx.x;
    const int lane = t & 63;
    const int w    = t >> 6;            // 0..7
    const int quad = lane >> 4;
    const int l15  = lane & 15;
    const int wm   = w >> 2, wn = w & 3;
    const int m0   = blockIdx.x * BM;
    const int n0   = blockIdx.y * BN;
    const int z    = blockIdx.z;

    const __bf16* A = Ag + (long)z * batchA;
    const __bf16* B = Bg + (long)z * batchB;

    // Staging: wave w owns rows [w*32, w*32+32) of both tiles, 2 loads each.
    // global_load_lds writes base + lane*16B -> row (lane>>2), slot lane&3.
    // Swizzle: slot s of row R holds k-chunk q = s ^ ((R>>1)&3); with
    // R = 16c + (lane>>2): q = (lane&3) ^ ((lane>>3)&3).
    const int srow = lane >> 2;
    const int sq   = ((lane & 3) ^ ((lane >> 3) & 3)) * 8;
    const __bf16* ap0 = A + (long)(m0 + w * 32 +      srow) * lda + sq;
    const __bf16* ap1 = A + (long)(m0 + w * 32 + 16 + srow) * lda + sq;
    const __bf16* bp0 = B + (long)(n0 + w * 32 +      srow) * ldb + sq;
    const __bf16* bp1 = B + (long)(n0 + w * 32 + 16 + srow) * ldb + sq;
    const int wA = w * 1024;            // elem offset of wave's staging region

    // Read side: fragment row R = half + m*16 + l15, chunk quad,
    // slot = quad ^ ((R>>1)&3) = quad ^ ((l15>>1)&3).
    // Bank check: quarter-wave granule G = 4*(R&1) + slot hits all 8 16B
    // granules across 8 rows -> minimal 2-lane aliasing, conflict-free.
    const int swz = (quad ^ ((l15 >> 1) & 3)) * 8;
    const int raA = (wm * 128 + l15) * BK + swz;   // + m*512 per fragment
    const int raB = (wn * 64  + l15) * BK + swz;   // + n*512 per fragment

    f32x4 acc[8][4];
    #pragma unroll
    for (int i = 0; i < 8; ++i)
        #pragma unroll
        for (int j = 0; j < 4; ++j) acc[i][j] = (f32x4)(0.0f);

    const int NT = K / BK;

    // ---- prologue: stage tiles 0,1,2 (12 loads/wave), wait tile 0 ----
    #pragma unroll
    for (int i = 0; i < 3; ++i) {
        gload_lds16(ap0, &As[i][wA]);
        gload_lds16(ap1, &As[i][wA + 512]);
        gload_lds16(bp0, &Bs[i][wA]);
        gload_lds16(bp1, &Bs[i][wA + 512]);
        ap0 += BK; ap1 += BK; bp0 += BK; bp1 += BK;
    }
    asm volatile("s_waitcnt vmcnt(8)" ::: "memory");  // tile 0 resident
    __builtin_amdgcn_s_barrier();

    // ---- main loop: compute tile t, stage tile t+3 into buffer (t+3)&3
    // (that buffer was last read at tile t-1; freed by its end barrier).
    // vmcnt(8) leaves tiles t+2,t+3 in flight, guarantees t+1 resident. ----
    for (int tt = 0; tt < NT - 3; ++tt) {
        const int b = tt & 3, nb = (tt + 3) & 3;
        TILE_STEP(b, nb, 1, asm volatile("s_waitcnt vmcnt(8)" ::: "memory"));
    }
    // ---- epilogue tiles: no staging, drain 4 -> 0 ----
    TILE_STEP((NT - 3) & 3, 0, 0, asm volatile("s_waitcnt vmcnt(4)" ::: "memory"));
    TILE_STEP((NT - 2) & 3, 0, 0, asm volatile("s_waitcnt vmcnt(0)" ::: "memory"));
    TILE_STEP((NT - 1) & 3, 0, 0, ((void)0));

    const int rowbase = m0 + wm * 128;
    const int colbase = n0 + wn * 64;

    if constexpr (MODE == MODE_PROJ) {
        __bf16* C = (__bf16*)Cg;
        #pragma unroll
        for (int n = 0; n < 4; ++n) {
            const int col = colbase + n * 16 + l15;
            const float bv = aux[col];
            #pragma unroll
            for (int m = 0; m < 8; ++m)
                #pragma unroll
                for (int r = 0; r < 4; ++r) {
                    const int row = rowbase + m * 16 + quad * 4 + r;
                    C[(long)row * ldc + col] = (__bf16)(acc[m][n][r] + bv);
                }
        }
    } else if constexpr (MODE == MODE_PROJT) {
        // C logical [1024 x 32768] -> stored per-batch [16][1024][2048]
        __bf16* C = (__bf16*)Cg;
        #pragma unroll
        for (int m = 0; m < 8; ++m)
            #pragma unroll
            for (int r = 0; r < 4; ++r) {
                const int row = rowbase + m * 16 + quad * 4 + r;
                const float bv = aux[row];
                #pragma unroll
                for (int n = 0; n < 4; ++n) {
                    const int col = colbase + n * 16 + l15;   // global key idx
                    const long idx = (long)(col >> 11) * (1024L * 2048)
                                   + (long)row * 2048 + (col & 2047);
                    C[idx] = (__bf16)(acc[m][n][r] + bv);
                }
            }
    } else if constexpr (MODE == MODE_SCORE) {
        const float sc = 0.03125f * 1.44269504088896f;  // (1/sqrt(1024))*log2e
        __bf16* C = (__bf16*)Cg + (long)z * batchC;
        float* rsz = rs + (long)z * batchRS;
        #pragma unroll
        for (int m = 0; m < 8; ++m) {
            float s[4] = {0.f, 0.f, 0.f, 0.f};
            #pragma unroll
            for (int n = 0; n < 4; ++n) {
                const int col = colbase + n * 16 + l15;
                #pragma unroll
                for (int r = 0; r < 4; ++r) {
                    const int row = rowbase + m * 16 + quad * 4 + r;
                    const float e = exp2f(acc[m][n][r] * sc);
                    C[(long)row * ldc + col] = (__bf16)e;
                    s[r] += e;
                }
            }
            #pragma unroll
            for (int r = 0; r < 4; ++r) {
                float v = s[r];
                v += __shfl_xor(v, 1);
                v += __shfl_xor(v, 2);
                v += __shfl_xor(v, 4);
                v += __shfl_xor(v, 8);
                if (l15 == 0)
                    atomicAdd(&rsz[rowbase + m * 16 + quad * 4 + r], v);
            }
        }
    } else {  // MODE_PV
        float* C = (float*)Cg + (long)z * batchC;
        const float* rsz = rs + (long)z * batchRS;
        #pragma unroll
        for (int m = 0; m < 8; ++m) {
            float inv[4];
            #pragma unroll
            for (int r = 0; r < 4; ++r)
                inv[r] = 1.0f / rsz[rowbase + m * 16 + quad * 4 + r];
            #pragma unroll
            for (int n = 0; n < 4; ++n) {
                const int col = colbase + n * 16 + l15;
                #pragma unroll
                for (int r = 0; r < 4; ++r) {
                    const int row = rowbase + m * 16 + quad * 4 + r;
                    C[(long)row * ldc + col] = acc[m][n][r] * inv[r];
                }
            }
        }
    }
}

// ---------------------------------------------------------------------------
// fp32 -> bf16 elementwise convert (vectorized x8, grid-stride)
// ---------------------------------------------------------------------------
__global__ __launch_bounds__(256) void conv_bf16(const float* __restrict__ in,
                                                 __bf16* __restrict__ out, long n8)
{
    const long stride = (long)gridDim.x * blockDim.x;
    for (long i = (long)blockIdx.x * blockDim.x + threadIdx.x; i < n8; i += stride) {
        const float4* p = (const float4*)(in + i * 8);
        const float4 a = p[0], b = p[1];
        bf16x8 o;
        o[0] = (__bf16)a.x; o[1] = (__bf16)a.y; o[2] = (__bf16)a.z; o[3] = (__bf16)a.w;
        o[4] = (__bf16)b.x; o[5] = (__bf16)b.y; o[6] = (__bf16)b.z; o[7] = (__bf16)b.w;
        *(bf16x8*)(out + i * 8) = o;
    }
}

// ---------------------------------------------------------------------------
// W [K][N] fp32 -> WT [N][K] bf16, LDS-tiled 32x32 transpose
// ---------------------------------------------------------------------------
__global__ __launch_bounds__(256) void transpose_w(const float* __restrict__ W,
                                                   __bf16* __restrict__ WT,
                                                   int K, int N)
{
    __shared__ float tile[32][33];
    const int n0 = blockIdx.x * 32, k0 = blockIdx.y * 32;
    const int c = threadIdx.x & 31, r4 = threadIdx.x >> 5;
    #pragma unroll
    for (int i = 0; i < 4; ++i) {
        const int r = r4 + i * 8;
        tile[r][c] = W[(long)(k0 + r) * N + n0 + c];
    }
    __syncthreads();
    #pragma unroll
    for (int i = 0; i < 4; ++i) {
        const int r = r4 + i * 8;
        WT[(long)(n0 + r) * K + k0 + c] = (__bf16)tile[c][r];
    }
}

// ---------------------------------------------------------------------------
extern "C" void kernel_launch(void* const* d_in, const int* in_sizes, int n_in,
                              void* d_out, int out_size, void* d_ws, size_t ws_size,
                              hipStream_t stream) {
    const float* query = (const float*)d_in[0];  // [16,2048,768]
    const float* key   = (const float*)d_in[1];  // [16,2048,1024]
    const float* Wq    = (const float*)d_in[2];  // [768,1024]
    const float* bq    = (const float*)d_in[3];
    const float* Wk    = (const float*)d_in[4];  // [1024,1024]
    const float* bk    = (const float*)d_in[5];
    const float* Wv    = (const float*)d_in[6];  // [1024,1024]
    const float* bv    = (const float*)d_in[7];
    float* out = (float*)d_out;                  // [16,2048,1024]

    const int B = 16, Lq = 2048, Lk = 2048, Dq = 768, Dk = 1024;
    const long M = (long)B * Lq;                 // 32768

    char* base = (char*)d_ws;
    // Phase-1 scratch lives inside the P region (dead before score writes P).
    __bf16* P   = (__bf16*)base;                            // 128 MiB
    __bf16* qa  = (__bf16*)base;                            //  48 MiB (in P)
    __bf16* ka  = (__bf16*)(base + 50331648);               //  64 MiB (in P)
    __bf16* WqT = (__bf16*)(base + 117440512);              // 1.5 MiB (in P)
    __bf16* WkT = (__bf16*)(base + 119013376);              //   2 MiB (in P)
    __bf16* WvT = (__bf16*)(base + 121110528);              //   2 MiB (in P)
    char* p2 = base + 134217728;
    __bf16* q  = (__bf16*)p2;  p2 += M * Dk * 2;            // 64 MiB
    __bf16* k  = (__bf16*)p2;  p2 += M * Dk * 2;            // 64 MiB
    __bf16* vT = (__bf16*)p2;  p2 += M * Dk * 2;            // 64 MiB [16][1024][2048]
    float* row_sum = (float*)p2; p2 += M * 4;               // 128 KiB
    if ((size_t)(p2 - base) > ws_size) return;  // loud absmax fail if ws too small

    dim3 blk(256);
    dim3 blk5(512);

    // pre-pass: bf16 conversions + weight transposes
    conv_bf16<<<512, blk, 0, stream>>>(query, qa, M * Dq / 8);
    conv_bf16<<<512, blk, 0, stream>>>(key,   ka, M * Dk / 8);
    transpose_w<<<dim3(Dk / 32, Dq / 32), blk, 0, stream>>>(Wq, WqT, Dq, Dk);
    transpose_w<<<dim3(Dk / 32, Dk / 32), blk, 0, stream>>>(Wk, WkT, Dk, Dk);
    transpose_w<<<dim3(Dk / 32, Dk / 32), blk, 0, stream>>>(Wv, WvT, Dk, Dk);
    hipMemsetAsync(row_sum, 0, M * 4, stream);

    // projections
    gemm256<MODE_PROJ><<<dim3(M / BM, Dk / BN, 1), blk5, 0, stream>>>(
        qa, WqT, bq, nullptr, q, Dq, Dq, Dq, Dk, 0, 0, 0, 0);
    gemm256<MODE_PROJ><<<dim3(M / BM, Dk / BN, 1), blk5, 0, stream>>>(
        ka, WkT, bk, nullptr, k, Dk, Dk, Dk, Dk, 0, 0, 0, 0);
    // vT = WvT @ ka^T + bv(per-row): stored per-batch [16][1024][2048]
    gemm256<MODE_PROJT><<<dim3(Dk / BM, M / BN, 1), blk5, 0, stream>>>(
        WvT, ka, bv, nullptr, vT, Dk, Dk, Dk, 0, 0, 0, 0, 0);

    // scores: P = exp(q k^T / 32), row_sum via atomics
    gemm256<MODE_SCORE><<<dim3(Lq / BM, Lk / BN, B), blk5, 0, stream>>>(
        q, k, nullptr, row_sum, P, Dk, Dk, Dk, Lk,
        (long)Lq * Dk, (long)Lk * Dk, (long)Lq * Lk, Lq);

    // out = (P @ vT^T) / row_sum   (vT per-batch: ldb=2048, batchB=1024*2048)
    gemm256<MODE_PV><<<dim3(Lq / BM, Dk / BN, B), blk5, 0, stream>>>(
        P, vT, nullptr, row_sum, out, Lk, Lk, 2048, Dk,
        (long)Lq * Lk, 1024L * 2048, (long)Lq * Dk, Lq);
}

// Round 2
// 986.822 us; speedup vs baseline: 1.0190x; 1.0084x over previous
//
#include <hip/hip_runtime.h>
#include <hip/hip_bf16.h>

// CrossAttention: B=16, Lq=Lk=2048, Dq=768, Dk=1024, fp32 in/out.
// 256x256 tile, BK=32, 8 waves (2x4), 16x16x32 bf16 MFMA.
// Phase-scheduled pipeline (T2+T3+T4+T5), m201-faithful asm discipline:
//   - NO memory-clobber fences (they force hidden vmcnt(0) drains)
//   - counted s_waitcnt vmcnt(8) once per K-tile, bare asm volatile
//   - compiler-emitted fine-grained lgkmcnt for ds_read->MFMA (m97-verified)
//   - 4-deep LDS buffer rotation (128 KiB), stage tile t+3 during tile t
//   - XOR-swizzled staging (inverse-swizzled global source, swizzled ds_read)
// Pipeline: q = qa@WqT^T+bq ; k = ka@WkT^T+bk ; vT = WvT@ka^T+bv (per-batch)
//           P = exp(q k^T/32) bf16 + fp32 row_sum ; out = (P@vT^T)/row_sum

typedef __attribute__((ext_vector_type(4))) float  f32x4;
typedef __attribute__((ext_vector_type(8))) __bf16 bf16x8;

#define BM 256
#define BN 256
#define BK 32

__device__ __forceinline__ void gload_lds16(const __bf16* g, __bf16* l) {
    __builtin_amdgcn_global_load_lds(
        (const __attribute__((address_space(1))) void*)g,
        (__attribute__((address_space(3))) void*)l, 16, 0, 0);
}

enum { MODE_PROJ = 0, MODE_PROJT = 1, MODE_SCORE = 2, MODE_PV = 3 };

// 4 MFMAs of one m-row against b0..b3
#define MF(m_, a_)                                                              \
    acc[m_][0] = __builtin_amdgcn_mfma_f32_16x16x32_bf16(a_, b0, acc[m_][0], 0, 0, 0); \
    acc[m_][1] = __builtin_amdgcn_mfma_f32_16x16x32_bf16(a_, b1, acc[m_][1], 0, 0, 0); \
    acc[m_][2] = __builtin_amdgcn_mfma_f32_16x16x32_bf16(a_, b2, acc[m_][2], 0, 0, 0); \
    acc[m_][3] = __builtin_amdgcn_mfma_f32_16x16x32_bf16(a_, b3, acc[m_][3], 0, 0, 0);

// One K-tile = 2 phases x 16 MFMA. B_ = buffer to compute from, NB_ = buffer
// to stage tile t+3 into. VM_WAIT = counted vmcnt guaranteeing tile t+1 ready.
// b-frags read first so the compiler's fine-grained lgkm waits let MF(0) start
// while a1..a3 still drain.
#define TILE_STEP(B_, NB_, DO_STAGE, VM_WAIT) do {                              \
    const __bf16* __restrict__ Ab = As[B_];                                     \
    const __bf16* __restrict__ Bb = Bs[B_];                                     \
    bf16x8 a0, a1, a2, a3, a4, a5, a6, a7, b0, b1, b2, b3;                      \
    /* ---- phase 1: reads + A-stage ---- */                                    \
    b0 = *(const bf16x8*)&Bb[raB];                                              \
    b1 = *(const bf16x8*)&Bb[raB + 512];                                        \
    b2 = *(const bf16x8*)&Bb[raB + 1024];                                       \
    b3 = *(const bf16x8*)&Bb[raB + 1536];                                       \
    a0 = *(const bf16x8*)&Ab[raA];                                              \
    a1 = *(const bf16x8*)&Ab[raA + 512];                                        \
    a2 = *(const bf16x8*)&Ab[raA + 1024];                                       \
    a3 = *(const bf16x8*)&Ab[raA + 1536];                                       \
    if (DO_STAGE) {                                                             \
        gload_lds16(ap0, &As[NB_][wA]);                                         \
        gload_lds16(ap1, &As[NB_][wA + 512]);                                   \
        ap0 += BK; ap1 += BK;                                                   \
    }                                                                           \
    __builtin_amdgcn_s_barrier();                                               \
    __builtin_amdgcn_s_setprio(1);                                              \
    MF(0, a0) MF(1, a1) MF(2, a2) MF(3, a3)                                     \
    __builtin_amdgcn_s_setprio(0);                                              \
    __builtin_amdgcn_s_barrier();                                               \
    /* ---- phase 2: reads + B-stage + counted vmcnt ---- */                    \
    a4 = *(const bf16x8*)&Ab[raA + 2048];                                       \
    a5 = *(const bf16x8*)&Ab[raA + 2560];                                       \
    a6 = *(const bf16x8*)&Ab[raA + 3072];                                       \
    a7 = *(const bf16x8*)&Ab[raA + 3584];                                       \
    if (DO_STAGE) {                                                             \
        gload_lds16(bp0, &Bs[NB_][wA]);                                         \
        gload_lds16(bp1, &Bs[NB_][wA + 512]);                                   \
        bp0 += BK; bp1 += BK;                                                   \
    }                                                                           \
    VM_WAIT;                                                                    \
    __builtin_amdgcn_s_barrier();                                               \
    __builtin_amdgcn_s_setprio(1);                                              \
    MF(4, a4) MF(5, a5) MF(6, a6) MF(7, a7)                                     \
    __builtin_amdgcn_s_setprio(0);                                              \
    __builtin_amdgcn_s_barrier();                                               \
} while (0)

// ---------------------------------------------------------------------------
// Unified 256x256 NT GEMM: C[m][n] = sum_k A[m][k] * B[n][k]  (+ epilogue)
// ---------------------------------------------------------------------------
template <int MODE>
__global__ __launch_bounds__(512, 2) void gemm256(
    const __bf16* __restrict__ Ag, const __bf16* __restrict__ Bg,
    const float* __restrict__ aux,   // bias (PROJ: per-col, PROJT: per-row)
    float* __restrict__ rs,          // row_sum (SCORE: atomic out, PV: in)
    void* __restrict__ Cg,
    int K, int lda, int ldb, int ldc,
    long batchA, long batchB, long batchC, long batchRS)
{
    __shared__ __bf16 As[4][BM * BK];   // 4 x 16 KiB
    __shared__ __bf16 Bs[4][BN * BK];   // 4 x 16 KiB
    const int t    = threadIdx.x;
    const int lane = t & 63;
    const int w    = t >> 6;            // 0..7
    const int quad = lane >> 4;
    const int l15  = lane & 15;
    const int wm   = w >> 2, wn = w & 3;
    const int m0   = blockIdx.x * BM;
    const int n0   = blockIdx.y * BN;
    const int z    = blockIdx.z;

    const __bf16* A = Ag + (long)z * batchA;
    const __bf16* B = Bg + (long)z * batchB;

    // Staging: wave w owns rows [w*32, w*32+32) of both tiles, 2 loads each.
    // global_load_lds writes base + lane*16B -> row (lane>>2), slot lane&3.
    // Swizzle: slot s of row R holds k-chunk q = s ^ ((R>>1)&3); with
    // R = 16c + (lane>>2): q = (lane&3) ^ ((lane>>3)&3).
    const int srow = lane >> 2;
    const int sq   = ((lane & 3) ^ ((lane >> 3) & 3)) * 8;
    const __bf16* ap0 = A + (long)(m0 + w * 32 +      srow) * lda + sq;
    const __bf16* ap1 = A + (long)(m0 + w * 32 + 16 + srow) * lda + sq;
    const __bf16* bp0 = B + (long)(n0 + w * 32 +      srow) * ldb + sq;
    const __bf16* bp1 = B + (long)(n0 + w * 32 + 16 + srow) * ldb + sq;
    const int wA = w * 1024;            // elem offset of wave's staging region

    // Read side: fragment row R = half + m*16 + l15, chunk quad,
    // slot = quad ^ ((R>>1)&3) = quad ^ ((l15>>1)&3).
    // Bank check: quarter-wave granule G = 4*(R&1) + slot hits all 8 16B
    // granules across 8 rows -> minimal 2-lane aliasing, conflict-free.
    const int swz = (quad ^ ((l15 >> 1) & 3)) * 8;
    const int raA = (wm * 128 + l15) * BK + swz;   // + m*512 per fragment
    const int raB = (wn * 64  + l15) * BK + swz;   // + n*512 per fragment

    f32x4 acc[8][4];
    #pragma unroll
    for (int i = 0; i < 8; ++i)
        #pragma unroll
        for (int j = 0; j < 4; ++j) acc[i][j] = (f32x4)(0.0f);

    const int NT = K / BK;

    // ---- prologue: stage tiles 0,1,2 (12 loads/wave), wait tile 0 ----
    #pragma unroll
    for (int i = 0; i < 3; ++i) {
        gload_lds16(ap0, &As[i][wA]);
        gload_lds16(ap1, &As[i][wA + 512]);
        gload_lds16(bp0, &Bs[i][wA]);
        gload_lds16(bp1, &Bs[i][wA + 512]);
        ap0 += BK; ap1 += BK; bp0 += BK; bp1 += BK;
    }
    asm volatile("s_waitcnt vmcnt(8)");   // tile 0 resident
    __builtin_amdgcn_s_barrier();

    // ---- main loop: compute tile t, stage tile t+3 into buffer (t+3)&3
    // (that buffer was last read at tile t-1; freed by its end barrier).
    // vmcnt(8) leaves tiles t+2,t+3 in flight, guarantees t+1 resident. ----
    for (int tt = 0; tt < NT - 3; ++tt) {
        const int b = tt & 3, nb = (tt + 3) & 3;
        TILE_STEP(b, nb, 1, asm volatile("s_waitcnt vmcnt(8)"));
    }
    // ---- epilogue tiles: no staging, drain 4 -> 0 ----
    TILE_STEP((NT - 3) & 3, 0, 0, asm volatile("s_waitcnt vmcnt(4)"));
    TILE_STEP((NT - 2) & 3, 0, 0, asm volatile("s_waitcnt vmcnt(0)"));
    TILE_STEP((NT - 1) & 3, 0, 0, ((void)0));

    const int rowbase = m0 + wm * 128;
    const int colbase = n0 + wn * 64;

    if constexpr (MODE == MODE_PROJ) {
        __bf16* C = (__bf16*)Cg;
        #pragma unroll
        for (int n = 0; n < 4; ++n) {
            const int col = colbase + n * 16 + l15;
            const float bv = aux[col];
            #pragma unroll
            for (int m = 0; m < 8; ++m)
                #pragma unroll
                for (int r = 0; r < 4; ++r) {
                    const int row = rowbase + m * 16 + quad * 4 + r;
                    C[(long)row * ldc + col] = (__bf16)(acc[m][n][r] + bv);
                }
        }
    } else if constexpr (MODE == MODE_PROJT) {
        // C logical [1024 x 32768] -> stored per-batch [16][1024][2048]
        __bf16* C = (__bf16*)Cg;
        #pragma unroll
        for (int m = 0; m < 8; ++m)
            #pragma unroll
            for (int r = 0; r < 4; ++r) {
                const int row = rowbase + m * 16 + quad * 4 + r;
                const float bv = aux[row];
                #pragma unroll
                for (int n = 0; n < 4; ++n) {
                    const int col = colbase + n * 16 + l15;   // global key idx
                    const long idx = (long)(col >> 11) * (1024L * 2048)
                                   + (long)row * 2048 + (col & 2047);
                    C[idx] = (__bf16)(acc[m][n][r] + bv);
                }
            }
    } else if constexpr (MODE == MODE_SCORE) {
        const float sc = 0.03125f * 1.44269504088896f;  // (1/sqrt(1024))*log2e
        __bf16* C = (__bf16*)Cg + (long)z * batchC;
        float* rsz = rs + (long)z * batchRS;
        #pragma unroll
        for (int m = 0; m < 8; ++m) {
            float s[4] = {0.f, 0.f, 0.f, 0.f};
            #pragma unroll
            for (int n = 0; n < 4; ++n) {
                const int col = colbase + n * 16 + l15;
                #pragma unroll
                for (int r = 0; r < 4; ++r) {
                    const int row = rowbase + m * 16 + quad * 4 + r;
                    const float e = exp2f(acc[m][n][r] * sc);
                    C[(long)row * ldc + col] = (__bf16)e;
                    s[r] += e;
                }
            }
            #pragma unroll
            for (int r = 0; r < 4; ++r) {
                float v = s[r];
                v += __shfl_xor(v, 1);
                v += __shfl_xor(v, 2);
                v += __shfl_xor(v, 4);
                v += __shfl_xor(v, 8);
                if (l15 == 0)
                    atomicAdd(&rsz[rowbase + m * 16 + quad * 4 + r], v);
            }
        }
    } else {  // MODE_PV
        float* C = (float*)Cg + (long)z * batchC;
        const float* rsz = rs + (long)z * batchRS;
        #pragma unroll
        for (int m = 0; m < 8; ++m) {
            float inv[4];
            #pragma unroll
            for (int r = 0; r < 4; ++r)
                inv[r] = 1.0f / rsz[rowbase + m * 16 + quad * 4 + r];
            #pragma unroll
            for (int n = 0; n < 4; ++n) {
                const int col = colbase + n * 16 + l15;
                #pragma unroll
                for (int r = 0; r < 4; ++r) {
                    const int row = rowbase + m * 16 + quad * 4 + r;
                    C[(long)row * ldc + col] = acc[m][n][r] * inv[r];
                }
            }
        }
    }
}

// ---------------------------------------------------------------------------
// fp32 -> bf16 elementwise convert (vectorized x8, grid-stride)
// ---------------------------------------------------------------------------
__global__ __launch_bounds__(256) void conv_bf16(const float* __restrict__ in,
                                                 __bf16* __restrict__ out, long n8)
{
    const long stride = (long)gridDim.x * blockDim.x;
    for (long i = (long)blockIdx.x * blockDim.x + threadIdx.x; i < n8; i += stride) {
        const float4* p = (const float4*)(in + i * 8);
        const float4 a = p[0], b = p[1];
        bf16x8 o;
        o[0] = (__bf16)a.x; o[1] = (__bf16)a.y; o[2] = (__bf16)a.z; o[3] = (__bf16)a.w;
        o[4] = (__bf16)b.x; o[5] = (__bf16)b.y; o[6] = (__bf16)b.z; o[7] = (__bf16)b.w;
        *(bf16x8*)(out + i * 8) = o;
    }
}

// ---------------------------------------------------------------------------
// W [K][N] fp32 -> WT [N][K] bf16, LDS-tiled 32x32 transpose
// ---------------------------------------------------------------------------
__global__ __launch_bounds__(256) void transpose_w(const float* __restrict__ W,
                                                   __bf16* __restrict__ WT,
                                                   int K, int N)
{
    __shared__ float tile[32][33];
    const int n0 = blockIdx.x * 32, k0 = blockIdx.y * 32;
    const int c = threadIdx.x & 31, r4 = threadIdx.x >> 5;
    #pragma unroll
    for (int i = 0; i < 4; ++i) {
        const int r = r4 + i * 8;
        tile[r][c] = W[(long)(k0 + r) * N + n0 + c];
    }
    __syncthreads();
    #pragma unroll
    for (int i = 0; i < 4; ++i) {
        const int r = r4 + i * 8;
        WT[(long)(n0 + r) * K + k0 + c] = (__bf16)tile[c][r];
    }
}

// ---------------------------------------------------------------------------
extern "C" void kernel_launch(void* const* d_in, const int* in_sizes, int n_in,
                              void* d_out, int out_size, void* d_ws, size_t ws_size,
                              hipStream_t stream) {
    const float* query = (const float*)d_in[0];  // [16,2048,768]
    const float* key   = (const float*)d_in[1];  // [16,2048,1024]
    const float* Wq    = (const float*)d_in[2];  // [768,1024]
    const float* bq    = (const float*)d_in[3];
    const float* Wk    = (const float*)d_in[4];  // [1024,1024]
    const float* bk    = (const float*)d_in[5];
    const float* Wv    = (const float*)d_in[6];  // [1024,1024]
    const float* bv    = (const float*)d_in[7];
    float* out = (float*)d_out;                  // [16,2048,1024]

    const int B = 16, Lq = 2048, Lk = 2048, Dq = 768, Dk = 1024;
    const long M = (long)B * Lq;                 // 32768

    char* base = (char*)d_ws;
    // Phase-1 scratch lives inside the P region (dead before score writes P).
    __bf16* P   = (__bf16*)base;                            // 128 MiB
    __bf16* qa  = (__bf16*)base;                            //  48 MiB (in P)
    __bf16* ka  = (__bf16*)(base + 50331648);               //  64 MiB (in P)
    __bf16* WqT = (__bf16*)(base + 117440512);              // 1.5 MiB (in P)
    __bf16* WkT = (__bf16*)(base + 119013376);              //   2 MiB (in P)
    __bf16* WvT = (__bf16*)(base + 121110528);              //   2 MiB (in P)
    char* p2 = base + 134217728;
    __bf16* q  = (__bf16*)p2;  p2 += M * Dk * 2;            // 64 MiB
    __bf16* k  = (__bf16*)p2;  p2 += M * Dk * 2;            // 64 MiB
    __bf16* vT = (__bf16*)p2;  p2 += M * Dk * 2;            // 64 MiB [16][1024][2048]
    float* row_sum = (float*)p2; p2 += M * 4;               // 128 KiB
    if ((size_t)(p2 - base) > ws_size) return;  // loud absmax fail if ws too small

    dim3 blk(256);
    dim3 blk5(512);

    // pre-pass: bf16 conversions + weight transposes
    conv_bf16<<<512, blk, 0, stream>>>(query, qa, M * Dq / 8);
    conv_bf16<<<512, blk, 0, stream>>>(key,   ka, M * Dk / 8);
    transpose_w<<<dim3(Dk / 32, Dq / 32), blk, 0, stream>>>(Wq, WqT, Dq, Dk);
    transpose_w<<<dim3(Dk / 32, Dk / 32), blk, 0, stream>>>(Wk, WkT, Dk, Dk);
    transpose_w<<<dim3(Dk / 32, Dk / 32), blk, 0, stream>>>(Wv, WvT, Dk, Dk);
    hipMemsetAsync(row_sum, 0, M * 4, stream);

    // projections
    gemm256<MODE_PROJ><<<dim3(M / BM, Dk / BN, 1), blk5, 0, stream>>>(
        qa, WqT, bq, nullptr, q, Dq, Dq, Dq, Dk, 0, 0, 0, 0);
    gemm256<MODE_PROJ><<<dim3(M / BM, Dk / BN, 1), blk5, 0, stream>>>(
        ka, WkT, bk, nullptr, k, Dk, Dk, Dk, Dk, 0, 0, 0, 0);
    // vT = WvT @ ka^T + bv(per-row): stored per-batch [16][1024][2048]
    gemm256<MODE_PROJT><<<dim3(Dk / BM, M / BN, 1), blk5, 0, stream>>>(
        WvT, ka, bv, nullptr, vT, Dk, Dk, Dk, 0, 0, 0, 0, 0);

    // scores: P = exp(q k^T / 32), row_sum via atomics
    gemm256<MODE_SCORE><<<dim3(Lq / BM, Lk / BN, B), blk5, 0, stream>>>(
        q, k, nullptr, row_sum, P, Dk, Dk, Dk, Lk,
        (long)Lq * Dk, (long)Lk * Dk, (long)Lq * Lk, Lq);

    // out = (P @ vT^T) / row_sum   (vT per-batch: ldb=2048, batchB=1024*2048)
    gemm256<MODE_PV><<<dim3(Lq / BM, Dk / BN, B), blk5, 0, stream>>>(
        P, vT, nullptr, row_sum, out, Lk, Lk, 2048, Dk,
        (long)Lq * Lk, 1024L * 2048, (long)Lq * Dk, Lq);
}

// Round 3
// 914.738 us; speedup vs baseline: 1.0993x; 1.0788x over previous
//
#include <hip/hip_runtime.h>
#include <hip/hip_bf16.h>

// CrossAttention: B=16, Lq=Lk=2048, Dq=768, Dk=1024, fp32 in/out.
// 256x256 tile, BK=32, 8 waves (2x4), 16x16x32 bf16 MFMA.
// Phase-scheduled pipeline (T2+T3+T4+T5) with ALIAS-DISAMBIGUATED buffers:
//   - 8 distinct __shared__ arrays (As0..3 / Bs0..3) + compile-time buffer
//     names per TILE_STEP, so SIInsertWaitcnts can prove ds_read never
//     aliases a pending global_load_lds DMA -> no hidden per-phase vmcnt
//     drain (the round-1/2 killer).
//   - counted s_waitcnt vmcnt(8) once per K-tile, bare asm volatile
//   - compiler-emitted fine-grained lgkmcnt for ds_read->MFMA
//   - 4-deep LDS buffer rotation (128 KiB), stage tile t+3 during tile t
//   - XOR-swizzled staging (inverse-swizzled global source, swizzled ds_read)
// Pipeline: q = qa@WqT^T+bq ; k = ka@WkT^T+bk ; vT = WvT@ka^T+bv (per-batch)
//           P = exp(q k^T/32) bf16 + fp32 row_sum ; out = (P@vT^T)/row_sum

typedef __attribute__((ext_vector_type(4))) float  f32x4;
typedef __attribute__((ext_vector_type(8))) __bf16 bf16x8;

#define BM 256
#define BN 256
#define BK 32

__device__ __forceinline__ void gload_lds16(const __bf16* g, __bf16* l) {
    __builtin_amdgcn_global_load_lds(
        (const __attribute__((address_space(1))) void*)g,
        (__attribute__((address_space(3))) void*)l, 16, 0, 0);
}

enum { MODE_PROJ = 0, MODE_PROJT = 1, MODE_SCORE = 2, MODE_PV = 3 };

// 4 MFMAs of one m-row against b0..b3
#define MF(m_, a_)                                                              \
    acc[m_][0] = __builtin_amdgcn_mfma_f32_16x16x32_bf16(a_, b0, acc[m_][0], 0, 0, 0); \
    acc[m_][1] = __builtin_amdgcn_mfma_f32_16x16x32_bf16(a_, b1, acc[m_][1], 0, 0, 0); \
    acc[m_][2] = __builtin_amdgcn_mfma_f32_16x16x32_bf16(a_, b2, acc[m_][2], 0, 0, 0); \
    acc[m_][3] = __builtin_amdgcn_mfma_f32_16x16x32_bf16(a_, b3, acc[m_][3], 0, 0, 0);

// One K-tile = 2 phases x 16 MFMA. Compute from CA_/CB_, stage tile t+3 into
// SA_/SB_ (all compile-time array names -> NoAlias vs pending DMA).
// VM_WAIT = counted vmcnt guaranteeing tile t+1 resident.
#define TILE_STEP(CA_, CB_, SA_, SB_, DO_STAGE, VM_WAIT) do {                   \
    bf16x8 a0, a1, a2, a3, a4, a5, a6, a7, b0, b1, b2, b3;                      \
    /* ---- phase 1: reads + A-stage ---- */                                    \
    b0 = *(const bf16x8*)&CB_[raB];                                             \
    b1 = *(const bf16x8*)&CB_[raB + 512];                                       \
    b2 = *(const bf16x8*)&CB_[raB + 1024];                                      \
    b3 = *(const bf16x8*)&CB_[raB + 1536];                                      \
    a0 = *(const bf16x8*)&CA_[raA];                                             \
    a1 = *(const bf16x8*)&CA_[raA + 512];                                       \
    a2 = *(const bf16x8*)&CA_[raA + 1024];                                      \
    a3 = *(const bf16x8*)&CA_[raA + 1536];                                      \
    if (DO_STAGE) {                                                             \
        gload_lds16(ap0, &SA_[wA]);                                             \
        gload_lds16(ap1, &SA_[wA + 512]);                                       \
        ap0 += BK; ap1 += BK;                                                   \
    }                                                                           \
    __builtin_amdgcn_s_barrier();                                               \
    __builtin_amdgcn_s_setprio(1);                                              \
    MF(0, a0) MF(1, a1) MF(2, a2) MF(3, a3)                                     \
    __builtin_amdgcn_s_setprio(0);                                              \
    __builtin_amdgcn_s_barrier();                                               \
    /* ---- phase 2: reads + B-stage + counted vmcnt ---- */                    \
    a4 = *(const bf16x8*)&CA_[raA + 2048];                                      \
    a5 = *(const bf16x8*)&CA_[raA + 2560];                                      \
    a6 = *(const bf16x8*)&CA_[raA + 3072];                                      \
    a7 = *(const bf16x8*)&CA_[raA + 3584];                                      \
    if (DO_STAGE) {                                                             \
        gload_lds16(bp0, &SB_[wA]);                                             \
        gload_lds16(bp1, &SB_[wA + 512]);                                       \
        bp0 += BK; bp1 += BK;                                                   \
    }                                                                           \
    VM_WAIT;                                                                    \
    __builtin_amdgcn_s_barrier();                                               \
    __builtin_amdgcn_s_setprio(1);                                              \
    MF(4, a4) MF(5, a5) MF(6, a6) MF(7, a7)                                     \
    __builtin_amdgcn_s_setprio(0);                                              \
    __builtin_amdgcn_s_barrier();                                               \
} while (0)

// ---------------------------------------------------------------------------
// Unified 256x256 NT GEMM: C[m][n] = sum_k A[m][k] * B[n][k]  (+ epilogue)
// Requires K % 128 == 0 (NT multiple of 4, NT >= 8).
// ---------------------------------------------------------------------------
template <int MODE>
__global__ __launch_bounds__(512, 2) void gemm256(
    const __bf16* __restrict__ Ag, const __bf16* __restrict__ Bg,
    const float* __restrict__ aux,   // bias (PROJ: per-col, PROJT: per-row)
    float* __restrict__ rs,          // row_sum (SCORE: atomic out, PV: in)
    void* __restrict__ Cg,
    int K, int lda, int ldb, int ldc,
    long batchA, long batchB, long batchC, long batchRS)
{
    // 4-deep rotation as DISTINCT objects (alias disambiguation for LDS DMA).
    __shared__ __bf16 As0[BM * BK], As1[BM * BK], As2[BM * BK], As3[BM * BK];
    __shared__ __bf16 Bs0[BN * BK], Bs1[BN * BK], Bs2[BN * BK], Bs3[BN * BK];
    const int t    = threadIdx.x;
    const int lane = t & 63;
    const int w    = t >> 6;            // 0..7
    const int quad = lane >> 4;
    const int l15  = lane & 15;
    const int wm   = w >> 2, wn = w & 3;
    const int m0   = blockIdx.x * BM;
    const int n0   = blockIdx.y * BN;
    const int z    = blockIdx.z;

    const __bf16* A = Ag + (long)z * batchA;
    const __bf16* B = Bg + (long)z * batchB;

    // Staging: wave w owns rows [w*32, w*32+32) of both tiles, 2 loads each.
    // global_load_lds writes base + lane*16B -> row (lane>>2), slot lane&3.
    // Swizzle: slot s of row R holds k-chunk q = s ^ ((R>>1)&3); with
    // R = 16c + (lane>>2): q = (lane&3) ^ ((lane>>3)&3).
    const int srow = lane >> 2;
    const int sq   = ((lane & 3) ^ ((lane >> 3) & 3)) * 8;
    const __bf16* ap0 = A + (long)(m0 + w * 32 +      srow) * lda + sq;
    const __bf16* ap1 = A + (long)(m0 + w * 32 + 16 + srow) * lda + sq;
    const __bf16* bp0 = B + (long)(n0 + w * 32 +      srow) * ldb + sq;
    const __bf16* bp1 = B + (long)(n0 + w * 32 + 16 + srow) * ldb + sq;
    const int wA = w * 1024;            // elem offset of wave's staging region

    // Read side: fragment row R = half + m*16 + l15, chunk quad,
    // slot = quad ^ ((R>>1)&3) = quad ^ ((l15>>1)&3).
    const int swz = (quad ^ ((l15 >> 1) & 3)) * 8;
    const int raA = (wm * 128 + l15) * BK + swz;   // + m*512 per fragment
    const int raB = (wn * 64  + l15) * BK + swz;   // + n*512 per fragment

    f32x4 acc[8][4];
    #pragma unroll
    for (int i = 0; i < 8; ++i)
        #pragma unroll
        for (int j = 0; j < 4; ++j) acc[i][j] = (f32x4)(0.0f);

    const int NT = K / BK;              // multiple of 4

    // ---- prologue: stage tiles 0,1,2 into bufs 0,1,2 (12 loads/wave) ----
    gload_lds16(ap0, &As0[wA]); gload_lds16(ap1, &As0[wA + 512]);
    gload_lds16(bp0, &Bs0[wA]); gload_lds16(bp1, &Bs0[wA + 512]);
    ap0 += BK; ap1 += BK; bp0 += BK; bp1 += BK;
    gload_lds16(ap0, &As1[wA]); gload_lds16(ap1, &As1[wA + 512]);
    gload_lds16(bp0, &Bs1[wA]); gload_lds16(bp1, &Bs1[wA + 512]);
    ap0 += BK; ap1 += BK; bp0 += BK; bp1 += BK;
    gload_lds16(ap0, &As2[wA]); gload_lds16(ap1, &As2[wA + 512]);
    gload_lds16(bp0, &Bs2[wA]); gload_lds16(bp1, &Bs2[wA + 512]);
    ap0 += BK; ap1 += BK; bp0 += BK; bp1 += BK;
    asm volatile("s_waitcnt vmcnt(8)");   // tile 0 resident
    __builtin_amdgcn_s_barrier();

    // ---- main loop: compute tile t (buf t&3), stage tile t+3 (buf (t+3)&3).
    // vmcnt(8) leaves tiles t+2,t+3 in flight, guarantees t+1 resident.
    // Chunked x4 so all buffer names are compile-time constants. ----
    const int chunks = (NT - 4) >> 2;   // covers tiles 0 .. NT-5
    for (int c = 0; c < chunks; ++c) {
        TILE_STEP(As0, Bs0, As3, Bs3, 1, asm volatile("s_waitcnt vmcnt(8)"));
        TILE_STEP(As1, Bs1, As0, Bs0, 1, asm volatile("s_waitcnt vmcnt(8)"));
        TILE_STEP(As2, Bs2, As1, Bs1, 1, asm volatile("s_waitcnt vmcnt(8)"));
        TILE_STEP(As3, Bs3, As2, Bs2, 1, asm volatile("s_waitcnt vmcnt(8)"));
    }
    // leftover main tile NT-4 (buf 0), stages tile NT-1 (buf 3)
    TILE_STEP(As0, Bs0, As3, Bs3, 1, asm volatile("s_waitcnt vmcnt(8)"));
    // ---- epilogue tiles NT-3,NT-2,NT-1 (bufs 1,2,3): drain 4 -> 0 ----
    TILE_STEP(As1, Bs1, As0, Bs0, 0, asm volatile("s_waitcnt vmcnt(4)"));
    TILE_STEP(As2, Bs2, As0, Bs0, 0, asm volatile("s_waitcnt vmcnt(0)"));
    TILE_STEP(As3, Bs3, As0, Bs0, 0, ((void)0));

    const int rowbase = m0 + wm * 128;
    const int colbase = n0 + wn * 64;

    if constexpr (MODE == MODE_PROJ) {
        __bf16* C = (__bf16*)Cg;
        #pragma unroll
        for (int n = 0; n < 4; ++n) {
            const int col = colbase + n * 16 + l15;
            const float bv = aux[col];
            #pragma unroll
            for (int m = 0; m < 8; ++m)
                #pragma unroll
                for (int r = 0; r < 4; ++r) {
                    const int row = rowbase + m * 16 + quad * 4 + r;
                    C[(long)row * ldc + col] = (__bf16)(acc[m][n][r] + bv);
                }
        }
    } else if constexpr (MODE == MODE_PROJT) {
        // C logical [1024 x 32768] -> stored per-batch [16][1024][2048]
        __bf16* C = (__bf16*)Cg;
        #pragma unroll
        for (int m = 0; m < 8; ++m)
            #pragma unroll
            for (int r = 0; r < 4; ++r) {
                const int row = rowbase + m * 16 + quad * 4 + r;
                const float bv = aux[row];
                #pragma unroll
                for (int n = 0; n < 4; ++n) {
                    const int col = colbase + n * 16 + l15;   // global key idx
                    const long idx = (long)(col >> 11) * (1024L * 2048)
                                   + (long)row * 2048 + (col & 2047);
                    C[idx] = (__bf16)(acc[m][n][r] + bv);
                }
            }
    } else if constexpr (MODE == MODE_SCORE) {
        const float sc = 0.03125f * 1.44269504088896f;  // (1/sqrt(1024))*log2e
        __bf16* C = (__bf16*)Cg + (long)z * batchC;
        float* rsz = rs + (long)z * batchRS;
        #pragma unroll
        for (int m = 0; m < 8; ++m) {
            float s[4] = {0.f, 0.f, 0.f, 0.f};
            #pragma unroll
            for (int n = 0; n < 4; ++n) {
                const int col = colbase + n * 16 + l15;
                #pragma unroll
                for (int r = 0; r < 4; ++r) {
                    const int row = rowbase + m * 16 + quad * 4 + r;
                    const float e = exp2f(acc[m][n][r] * sc);
                    C[(long)row * ldc + col] = (__bf16)e;
                    s[r] += e;
                }
            }
            #pragma unroll
            for (int r = 0; r < 4; ++r) {
                float v = s[r];
                v += __shfl_xor(v, 1);
                v += __shfl_xor(v, 2);
                v += __shfl_xor(v, 4);
                v += __shfl_xor(v, 8);
                if (l15 == 0)
                    atomicAdd(&rsz[rowbase + m * 16 + quad * 4 + r], v);
            }
        }
    } else {  // MODE_PV
        float* C = (float*)Cg + (long)z * batchC;
        const float* rsz = rs + (long)z * batchRS;
        #pragma unroll
        for (int m = 0; m < 8; ++m) {
            float inv[4];
            #pragma unroll
            for (int r = 0; r < 4; ++r)
                inv[r] = 1.0f / rsz[rowbase + m * 16 + quad * 4 + r];
            #pragma unroll
            for (int n = 0; n < 4; ++n) {
                const int col = colbase + n * 16 + l15;
                #pragma unroll
                for (int r = 0; r < 4; ++r) {
                    const int row = rowbase + m * 16 + quad * 4 + r;
                    C[(long)row * ldc + col] = acc[m][n][r] * inv[r];
                }
            }
        }
    }
}

// ---------------------------------------------------------------------------
// fp32 -> bf16 elementwise convert (vectorized x8, grid-stride)
// ---------------------------------------------------------------------------
__global__ __launch_bounds__(256) void conv_bf16(const float* __restrict__ in,
                                                 __bf16* __restrict__ out, long n8)
{
    const long stride = (long)gridDim.x * blockDim.x;
    for (long i = (long)blockIdx.x * blockDim.x + threadIdx.x; i < n8; i += stride) {
        const float4* p = (const float4*)(in + i * 8);
        const float4 a = p[0], b = p[1];
        bf16x8 o;
        o[0] = (__bf16)a.x; o[1] = (__bf16)a.y; o[2] = (__bf16)a.z; o[3] = (__bf16)a.w;
        o[4] = (__bf16)b.x; o[5] = (__bf16)b.y; o[6] = (__bf16)b.z; o[7] = (__bf16)b.w;
        *(bf16x8*)(out + i * 8) = o;
    }
}

// ---------------------------------------------------------------------------
// W [K][N] fp32 -> WT [N][K] bf16, LDS-tiled 32x32 transpose
// ---------------------------------------------------------------------------
__global__ __launch_bounds__(256) void transpose_w(const float* __restrict__ W,
                                                   __bf16* __restrict__ WT,
                                                   int K, int N)
{
    __shared__ float tile[32][33];
    const int n0 = blockIdx.x * 32, k0 = blockIdx.y * 32;
    const int c = threadIdx.x & 31, r4 = threadIdx.x >> 5;
    #pragma unroll
    for (int i = 0; i < 4; ++i) {
        const int r = r4 + i * 8;
        tile[r][c] = W[(long)(k0 + r) * N + n0 + c];
    }
    __syncthreads();
    #pragma unroll
    for (int i = 0; i < 4; ++i) {
        const int r = r4 + i * 8;
        WT[(long)(n0 + r) * K + k0 + c] = (__bf16)tile[c][r];
    }
}

// ---------------------------------------------------------------------------
extern "C" void kernel_launch(void* const* d_in, const int* in_sizes, int n_in,
                              void* d_out, int out_size, void* d_ws, size_t ws_size,
                              hipStream_t stream) {
    const float* query = (const float*)d_in[0];  // [16,2048,768]
    const float* key   = (const float*)d_in[1];  // [16,2048,1024]
    const float* Wq    = (const float*)d_in[2];  // [768,1024]
    const float* bq    = (const float*)d_in[3];
    const float* Wk    = (const float*)d_in[4];  // [1024,1024]
    const float* bk    = (const float*)d_in[5];
    const float* Wv    = (const float*)d_in[6];  // [1024,1024]
    const float* bv    = (const float*)d_in[7];
    float* out = (float*)d_out;                  // [16,2048,1024]

    const int B = 16, Lq = 2048, Lk = 2048, Dq = 768, Dk = 1024;
    const long M = (long)B * Lq;                 // 32768

    char* base = (char*)d_ws;
    // Phase-1 scratch lives inside the P region (dead before score writes P).
    __bf16* P   = (__bf16*)base;                            // 128 MiB
    __bf16* qa  = (__bf16*)base;                            //  48 MiB (in P)
    __bf16* ka  = (__bf16*)(base + 50331648);               //  64 MiB (in P)
    __bf16* WqT = (__bf16*)(base + 117440512);              // 1.5 MiB (in P)
    __bf16* WkT = (__bf16*)(base + 119013376);              //   2 MiB (in P)
    __bf16* WvT = (__bf16*)(base + 121110528);              //   2 MiB (in P)
    char* p2 = base + 134217728;
    __bf16* q  = (__bf16*)p2;  p2 += M * Dk * 2;            // 64 MiB
    __bf16* k  = (__bf16*)p2;  p2 += M * Dk * 2;            // 64 MiB
    __bf16* vT = (__bf16*)p2;  p2 += M * Dk * 2;            // 64 MiB [16][1024][2048]
    float* row_sum = (float*)p2; p2 += M * 4;               // 128 KiB
    if ((size_t)(p2 - base) > ws_size) return;  // loud absmax fail if ws too small

    dim3 blk(256);
    dim3 blk5(512);

    // pre-pass: bf16 conversions + weight transposes
    conv_bf16<<<512, blk, 0, stream>>>(query, qa, M * Dq / 8);
    conv_bf16<<<512, blk, 0, stream>>>(key,   ka, M * Dk / 8);
    transpose_w<<<dim3(Dk / 32, Dq / 32), blk, 0, stream>>>(Wq, WqT, Dq, Dk);
    transpose_w<<<dim3(Dk / 32, Dk / 32), blk, 0, stream>>>(Wk, WkT, Dk, Dk);
    transpose_w<<<dim3(Dk / 32, Dk / 32), blk, 0, stream>>>(Wv, WvT, Dk, Dk);
    hipMemsetAsync(row_sum, 0, M * 4, stream);

    // projections
    gemm256<MODE_PROJ><<<dim3(M / BM, Dk / BN, 1), blk5, 0, stream>>>(
        qa, WqT, bq, nullptr, q, Dq, Dq, Dq, Dk, 0, 0, 0, 0);
    gemm256<MODE_PROJ><<<dim3(M / BM, Dk / BN, 1), blk5, 0, stream>>>(
        ka, WkT, bk, nullptr, k, Dk, Dk, Dk, Dk, 0, 0, 0, 0);
    // vT = WvT @ ka^T + bv(per-row): stored per-batch [16][1024][2048]
    gemm256<MODE_PROJT><<<dim3(Dk / BM, M / BN, 1), blk5, 0, stream>>>(
        WvT, ka, bv, nullptr, vT, Dk, Dk, Dk, 0, 0, 0, 0, 0);

    // scores: P = exp(q k^T / 32), row_sum via atomics
    gemm256<MODE_SCORE><<<dim3(Lq / BM, Lk / BN, B), blk5, 0, stream>>>(
        q, k, nullptr, row_sum, P, Dk, Dk, Dk, Lk,
        (long)Lq * Dk, (long)Lk * Dk, (long)Lq * Lk, Lq);

    // out = (P @ vT^T) / row_sum   (vT per-batch: ldb=2048, batchB=1024*2048)
    gemm256<MODE_PV><<<dim3(Lq / BM, Dk / BN, B), blk5, 0, stream>>>(
        P, vT, nullptr, row_sum, out, Lk, Lk, 2048, Dk,
        (long)Lq * Lk, 1024L * 2048, (long)Lq * Dk, Lq);
}

// Round 4
// 887.371 us; speedup vs baseline: 1.1332x; 1.0308x over previous
//
#include <hip/hip_runtime.h>
#include <hip/hip_bf16.h>

// CrossAttention: B=16, Lq=Lk=2048, Dq=768, Dk=1024, fp32 in/out.
// 256x256 tile, BK=32, 8 waves (2x4), 16x16x32 bf16 MFMA.
// REG-STAGED pipeline with fully DERIVED waits (no global_load_lds, no manual
// vmcnt): global_load_dwordx4 -> VGPR slots (2, parity) -> ds_write_b128 into
// 2 LDS buffers. All vmcnt/lgkm waits are compiler-derived from register
// deps, so no conservative LDS-DMA alias drains (the round-1..3 killer).
//   tile t: read buf[t&1]; ds_write regs(data t+1) -> buf[(t+1)&1];
//           global-load data(t+2) -> freed reg slot.  4 barriers/tile,
//           setprio around MFMA clusters, lgkm publish before end barrier.
// XOR-swizzled LDS (pre-swizzled global source + swizzled ds_read).
// Pipeline: q = qa@WqT^T+bq ; k = ka@WkT^T+bk ; vT = WvT@ka^T+bv (per-batch)
//           P = exp(q k^T/32) bf16 + fp32 row_sum ; out = (P@vT^T)/row_sum

typedef __attribute__((ext_vector_type(4))) float  f32x4;
typedef __attribute__((ext_vector_type(8))) __bf16 bf16x8;

#define BM 256
#define BN 256
#define BK 32

enum { MODE_PROJ = 0, MODE_PROJT = 1, MODE_SCORE = 2, MODE_PV = 3 };

// 4 MFMAs of one m-row against b0..b3
#define MF(m_, a_)                                                              \
    acc[m_][0] = __builtin_amdgcn_mfma_f32_16x16x32_bf16(a_, b0, acc[m_][0], 0, 0, 0); \
    acc[m_][1] = __builtin_amdgcn_mfma_f32_16x16x32_bf16(a_, b1, acc[m_][1], 0, 0, 0); \
    acc[m_][2] = __builtin_amdgcn_mfma_f32_16x16x32_bf16(a_, b2, acc[m_][2], 0, 0, 0); \
    acc[m_][3] = __builtin_amdgcn_mfma_f32_16x16x32_bf16(a_, b3, acc[m_][3], 0, 0, 0);

// One K-tile = 2 phases x 16 MFMA.
// CA_/CB_: compute buffers (tile t). WA_/WB_: buffers for tile t+1.
// w0..w3: reg slot holding data(t+1) (ds_write). l0..l3: reg slot to fill
// with data(t+2) (global load). All waits compiler-derived.
#define TILE_STEP(CA_, CB_, WA_, WB_, w0_, w1_, w2_, w3_,                       \
                  l0_, l1_, l2_, l3_, DO_WRITE, DO_LOAD) do {                   \
    bf16x8 a0, a1, a2, a3, a4, a5, a6, a7, b0, b1, b2, b3;                      \
    /* ---- phase 1: next-next-tile global loads, compute reads, writes ---- */ \
    if (DO_LOAD) {                                                              \
        l0_ = *(const bf16x8*)ap0; l1_ = *(const bf16x8*)ap1;                   \
        l2_ = *(const bf16x8*)bp0; l3_ = *(const bf16x8*)bp1;                   \
        ap0 += BK; ap1 += BK; bp0 += BK; bp1 += BK;                             \
    }                                                                           \
    b0 = *(const bf16x8*)&CB_[raB];                                             \
    b1 = *(const bf16x8*)&CB_[raB + 512];                                       \
    b2 = *(const bf16x8*)&CB_[raB + 1024];                                      \
    b3 = *(const bf16x8*)&CB_[raB + 1536];                                      \
    a0 = *(const bf16x8*)&CA_[raA];                                             \
    a1 = *(const bf16x8*)&CA_[raA + 512];                                       \
    a2 = *(const bf16x8*)&CA_[raA + 1024];                                      \
    a3 = *(const bf16x8*)&CA_[raA + 1536];                                      \
    if (DO_WRITE) {  /* counted vmcnt auto-derived from reg deps */             \
        *(bf16x8*)&WA_[wA + lane8]       = w0_;                                 \
        *(bf16x8*)&WA_[wA + 512 + lane8] = w1_;                                 \
        *(bf16x8*)&WB_[wA + lane8]       = w2_;                                 \
        *(bf16x8*)&WB_[wA + 512 + lane8] = w3_;                                 \
    }                                                                           \
    __builtin_amdgcn_s_barrier();                                               \
    __builtin_amdgcn_s_setprio(1);                                              \
    MF(0, a0) MF(1, a1) MF(2, a2) MF(3, a3)                                     \
    __builtin_amdgcn_s_setprio(0);                                              \
    if (DO_WRITE) asm volatile("s_waitcnt lgkmcnt(0)"); /* publish writes */    \
    __builtin_amdgcn_s_barrier();                                               \
    /* ---- phase 2 ---- */                                                     \
    a4 = *(const bf16x8*)&CA_[raA + 2048];                                      \
    a5 = *(const bf16x8*)&CA_[raA + 2560];                                      \
    a6 = *(const bf16x8*)&CA_[raA + 3072];                                      \
    a7 = *(const bf16x8*)&CA_[raA + 3584];                                      \
    __builtin_amdgcn_s_barrier();                                               \
    __builtin_amdgcn_s_setprio(1);                                              \
    MF(4, a4) MF(5, a5) MF(6, a6) MF(7, a7)                                     \
    __builtin_amdgcn_s_setprio(0);                                              \
    __builtin_amdgcn_s_barrier();                                               \
} while (0)

// ---------------------------------------------------------------------------
// Unified 256x256 NT GEMM: C[m][n] = sum_k A[m][k] * B[n][k]  (+ epilogue)
// Requires K % 64 == 0 (NT even, NT >= 4).
// ---------------------------------------------------------------------------
template <int MODE>
__global__ __launch_bounds__(512, 2) void gemm256(
    const __bf16* __restrict__ Ag, const __bf16* __restrict__ Bg,
    const float* __restrict__ aux,   // bias (PROJ: per-col, PROJT: per-row)
    float* __restrict__ rs,          // row_sum (SCORE: atomic out, PV: in)
    void* __restrict__ Cg,
    int K, int lda, int ldb, int ldc,
    long batchA, long batchB, long batchC, long batchRS)
{
    __shared__ __bf16 As0[BM * BK], As1[BM * BK];   // 2 x 16 KiB
    __shared__ __bf16 Bs0[BN * BK], Bs1[BN * BK];   // 2 x 16 KiB
    const int t    = threadIdx.x;
    const int lane = t & 63;
    const int w    = t >> 6;            // 0..7
    const int quad = lane >> 4;
    const int l15  = lane & 15;
    const int wm   = w >> 2, wn = w & 3;
    const int m0   = blockIdx.x * BM;
    const int n0   = blockIdx.y * BN;
    const int z    = blockIdx.z;

    const __bf16* A = Ag + (long)z * batchA;
    const __bf16* B = Bg + (long)z * batchB;

    // Staging: wave w owns rows [w*32, w*32+32) of both tiles, 2x16B per lane.
    // ds_write lands at region base + lane*16B -> row (lane>>2), slot lane&3.
    // Swizzle: slot s of row R holds k-chunk q = s ^ ((R>>1)&3); with
    // R = 16c + (lane>>2): q = (lane&3) ^ ((lane>>3)&3)  (pre-swizzled source).
    const int srow = lane >> 2;
    const int sq   = ((lane & 3) ^ ((lane >> 3) & 3)) * 8;
    const __bf16* ap0 = A + (long)(m0 + w * 32 +      srow) * lda + sq;
    const __bf16* ap1 = A + (long)(m0 + w * 32 + 16 + srow) * lda + sq;
    const __bf16* bp0 = B + (long)(n0 + w * 32 +      srow) * ldb + sq;
    const __bf16* bp1 = B + (long)(n0 + w * 32 + 16 + srow) * ldb + sq;
    const int wA    = w * 1024;         // elem offset of wave's staging region
    const int lane8 = lane * 8;

    // Read side: fragment row R = base + l15, chunk quad,
    // slot = quad ^ ((R>>1)&3) = quad ^ ((l15>>1)&3)  (base % 16 == 0).
    const int swz = (quad ^ ((l15 >> 1) & 3)) * 8;
    const int raA = (wm * 128 + l15) * BK + swz;   // + m*512 per fragment
    const int raB = (wn * 64  + l15) * BK + swz;   // + n*512 per fragment

    f32x4 acc[8][4];
    #pragma unroll
    for (int i = 0; i < 8; ++i)
        #pragma unroll
        for (int j = 0; j < 4; ++j) acc[i][j] = (f32x4)(0.0f);

    const int NT = K / BK;              // even

    // Reg slots: q* = data(even tile+2), r* = data(odd tile+2).
    bf16x8 q0, q1, q2, q3, r0, r1, r2, r3;

    // ---- prologue: data(0) -> LDS buf0 directly; data(1) -> slot r ----
    {
        bf16x8 t0 = *(const bf16x8*)ap0, t1 = *(const bf16x8*)ap1;
        bf16x8 t2 = *(const bf16x8*)bp0, t3 = *(const bf16x8*)bp1;
        ap0 += BK; ap1 += BK; bp0 += BK; bp1 += BK;
        r0 = *(const bf16x8*)ap0; r1 = *(const bf16x8*)ap1;
        r2 = *(const bf16x8*)bp0; r3 = *(const bf16x8*)bp1;
        ap0 += BK; ap1 += BK; bp0 += BK; bp1 += BK;
        *(bf16x8*)&As0[wA + lane8]       = t0;
        *(bf16x8*)&As0[wA + 512 + lane8] = t1;
        *(bf16x8*)&Bs0[wA + lane8]       = t2;
        *(bf16x8*)&Bs0[wA + 512 + lane8] = t3;
        asm volatile("s_waitcnt lgkmcnt(0)");
        __builtin_amdgcn_s_barrier();
    }

    // ---- main loop: tiles 0 .. NT-3 (all with write+load) ----
    for (int tt = 0; tt < NT - 2; tt += 2) {
        TILE_STEP(As0, Bs0, As1, Bs1, r0, r1, r2, r3, q0, q1, q2, q3, 1, 1);
        TILE_STEP(As1, Bs1, As0, Bs0, q0, q1, q2, q3, r0, r1, r2, r3, 1, 1);
    }
    // ---- tail: tile NT-2 (write only), tile NT-1 (compute only) ----
    TILE_STEP(As0, Bs0, As1, Bs1, r0, r1, r2, r3, q0, q1, q2, q3, 1, 0);
    TILE_STEP(As1, Bs1, As0, Bs0, q0, q1, q2, q3, r0, r1, r2, r3, 0, 0);

    const int rowbase = m0 + wm * 128;
    const int colbase = n0 + wn * 64;

    if constexpr (MODE == MODE_PROJ) {
        __bf16* C = (__bf16*)Cg;
        #pragma unroll
        for (int n = 0; n < 4; ++n) {
            const int col = colbase + n * 16 + l15;
            const float bv = aux[col];
            #pragma unroll
            for (int m = 0; m < 8; ++m)
                #pragma unroll
                for (int r = 0; r < 4; ++r) {
                    const int row = rowbase + m * 16 + quad * 4 + r;
                    C[(long)row * ldc + col] = (__bf16)(acc[m][n][r] + bv);
                }
        }
    } else if constexpr (MODE == MODE_PROJT) {
        // C logical [1024 x 32768] -> stored per-batch [16][1024][2048]
        __bf16* C = (__bf16*)Cg;
        #pragma unroll
        for (int m = 0; m < 8; ++m)
            #pragma unroll
            for (int r = 0; r < 4; ++r) {
                const int row = rowbase + m * 16 + quad * 4 + r;
                const float bv = aux[row];
                #pragma unroll
                for (int n = 0; n < 4; ++n) {
                    const int col = colbase + n * 16 + l15;   // global key idx
                    const long idx = (long)(col >> 11) * (1024L * 2048)
                                   + (long)row * 2048 + (col & 2047);
                    C[idx] = (__bf16)(acc[m][n][r] + bv);
                }
            }
    } else if constexpr (MODE == MODE_SCORE) {
        const float sc = 0.03125f * 1.44269504088896f;  // (1/sqrt(1024))*log2e
        __bf16* C = (__bf16*)Cg + (long)z * batchC;
        float* rsz = rs + (long)z * batchRS;
        #pragma unroll
        for (int m = 0; m < 8; ++m) {
            float s[4] = {0.f, 0.f, 0.f, 0.f};
            #pragma unroll
            for (int n = 0; n < 4; ++n) {
                const int col = colbase + n * 16 + l15;
                #pragma unroll
                for (int r = 0; r < 4; ++r) {
                    const int row = rowbase + m * 16 + quad * 4 + r;
                    const float e = exp2f(acc[m][n][r] * sc);
                    C[(long)row * ldc + col] = (__bf16)e;
                    s[r] += e;
                }
            }
            #pragma unroll
            for (int r = 0; r < 4; ++r) {
                float v = s[r];
                v += __shfl_xor(v, 1);
                v += __shfl_xor(v, 2);
                v += __shfl_xor(v, 4);
                v += __shfl_xor(v, 8);
                if (l15 == 0)
                    atomicAdd(&rsz[rowbase + m * 16 + quad * 4 + r], v);
            }
        }
    } else {  // MODE_PV
        float* C = (float*)Cg + (long)z * batchC;
        const float* rsz = rs + (long)z * batchRS;
        #pragma unroll
        for (int m = 0; m < 8; ++m) {
            float inv[4];
            #pragma unroll
            for (int r = 0; r < 4; ++r)
                inv[r] = 1.0f / rsz[rowbase + m * 16 + quad * 4 + r];
            #pragma unroll
            for (int n = 0; n < 4; ++n) {
                const int col = colbase + n * 16 + l15;
                #pragma unroll
                for (int r = 0; r < 4; ++r) {
                    const int row = rowbase + m * 16 + quad * 4 + r;
                    C[(long)row * ldc + col] = acc[m][n][r] * inv[r];
                }
            }
        }
    }
}

// ---------------------------------------------------------------------------
// fp32 -> bf16 elementwise convert (vectorized x8, grid-stride)
// ---------------------------------------------------------------------------
__global__ __launch_bounds__(256) void conv_bf16(const float* __restrict__ in,
                                                 __bf16* __restrict__ out, long n8)
{
    const long stride = (long)gridDim.x * blockDim.x;
    for (long i = (long)blockIdx.x * blockDim.x + threadIdx.x; i < n8; i += stride) {
        const float4* p = (const float4*)(in + i * 8);
        const float4 a = p[0], b = p[1];
        bf16x8 o;
        o[0] = (__bf16)a.x; o[1] = (__bf16)a.y; o[2] = (__bf16)a.z; o[3] = (__bf16)a.w;
        o[4] = (__bf16)b.x; o[5] = (__bf16)b.y; o[6] = (__bf16)b.z; o[7] = (__bf16)b.w;
        *(bf16x8*)(out + i * 8) = o;
    }
}

// ---------------------------------------------------------------------------
// W [K][N] fp32 -> WT [N][K] bf16, LDS-tiled 32x32 transpose
// ---------------------------------------------------------------------------
__global__ __launch_bounds__(256) void transpose_w(const float* __restrict__ W,
                                                   __bf16* __restrict__ WT,
                                                   int K, int N)
{
    __shared__ float tile[32][33];
    const int n0 = blockIdx.x * 32, k0 = blockIdx.y * 32;
    const int c = threadIdx.x & 31, r4 = threadIdx.x >> 5;
    #pragma unroll
    for (int i = 0; i < 4; ++i) {
        const int r = r4 + i * 8;
        tile[r][c] = W[(long)(k0 + r) * N + n0 + c];
    }
    __syncthreads();
    #pragma unroll
    for (int i = 0; i < 4; ++i) {
        const int r = r4 + i * 8;
        WT[(long)(n0 + r) * K + k0 + c] = (__bf16)tile[c][r];
    }
}

// ---------------------------------------------------------------------------
extern "C" void kernel_launch(void* const* d_in, const int* in_sizes, int n_in,
                              void* d_out, int out_size, void* d_ws, size_t ws_size,
                              hipStream_t stream) {
    const float* query = (const float*)d_in[0];  // [16,2048,768]
    const float* key   = (const float*)d_in[1];  // [16,2048,1024]
    const float* Wq    = (const float*)d_in[2];  // [768,1024]
    const float* bq    = (const float*)d_in[3];
    const float* Wk    = (const float*)d_in[4];  // [1024,1024]
    const float* bk    = (const float*)d_in[5];
    const float* Wv    = (const float*)d_in[6];  // [1024,1024]
    const float* bv    = (const float*)d_in[7];
    float* out = (float*)d_out;                  // [16,2048,1024]

    const int B = 16, Lq = 2048, Lk = 2048, Dq = 768, Dk = 1024;
    const long M = (long)B * Lq;                 // 32768

    char* base = (char*)d_ws;
    // Phase-1 scratch lives inside the P region (dead before score writes P).
    __bf16* P   = (__bf16*)base;                            // 128 MiB
    __bf16* qa  = (__bf16*)base;                            //  48 MiB (in P)
    __bf16* ka  = (__bf16*)(base + 50331648);               //  64 MiB (in P)
    __bf16* WqT = (__bf16*)(base + 117440512);              // 1.5 MiB (in P)
    __bf16* WkT = (__bf16*)(base + 119013376);              //   2 MiB (in P)
    __bf16* WvT = (__bf16*)(base + 121110528);              //   2 MiB (in P)
    char* p2 = base + 134217728;
    __bf16* q  = (__bf16*)p2;  p2 += M * Dk * 2;            // 64 MiB
    __bf16* k  = (__bf16*)p2;  p2 += M * Dk * 2;            // 64 MiB
    __bf16* vT = (__bf16*)p2;  p2 += M * Dk * 2;            // 64 MiB [16][1024][2048]
    float* row_sum = (float*)p2; p2 += M * 4;               // 128 KiB
    if ((size_t)(p2 - base) > ws_size) return;  // loud absmax fail if ws too small

    dim3 blk(256);
    dim3 blk5(512);

    // pre-pass: bf16 conversions + weight transposes
    conv_bf16<<<512, blk, 0, stream>>>(query, qa, M * Dq / 8);
    conv_bf16<<<512, blk, 0, stream>>>(key,   ka, M * Dk / 8);
    transpose_w<<<dim3(Dk / 32, Dq / 32), blk, 0, stream>>>(Wq, WqT, Dq, Dk);
    transpose_w<<<dim3(Dk / 32, Dk / 32), blk, 0, stream>>>(Wk, WkT, Dk, Dk);
    transpose_w<<<dim3(Dk / 32, Dk / 32), blk, 0, stream>>>(Wv, WvT, Dk, Dk);
    hipMemsetAsync(row_sum, 0, M * 4, stream);

    // projections
    gemm256<MODE_PROJ><<<dim3(M / BM, Dk / BN, 1), blk5, 0, stream>>>(
        qa, WqT, bq, nullptr, q, Dq, Dq, Dq, Dk, 0, 0, 0, 0);
    gemm256<MODE_PROJ><<<dim3(M / BM, Dk / BN, 1), blk5, 0, stream>>>(
        ka, WkT, bk, nullptr, k, Dk, Dk, Dk, Dk, 0, 0, 0, 0);
    // vT = WvT @ ka^T + bv(per-row): stored per-batch [16][1024][2048]
    gemm256<MODE_PROJT><<<dim3(Dk / BM, M / BN, 1), blk5, 0, stream>>>(
        WvT, ka, bv, nullptr, vT, Dk, Dk, Dk, 0, 0, 0, 0, 0);

    // scores: P = exp(q k^T / 32), row_sum via atomics
    gemm256<MODE_SCORE><<<dim3(Lq / BM, Lk / BN, B), blk5, 0, stream>>>(
        q, k, nullptr, row_sum, P, Dk, Dk, Dk, Lk,
        (long)Lq * Dk, (long)Lk * Dk, (long)Lq * Lk, Lq);

    // out = (P @ vT^T) / row_sum   (vT per-batch: ldb=2048, batchB=1024*2048)
    gemm256<MODE_PV><<<dim3(Lq / BM, Dk / BN, B), blk5, 0, stream>>>(
        P, vT, nullptr, row_sum, out, Lk, Lk, 2048, Dk,
        (long)Lq * Lk, 1024L * 2048, (long)Lq * Dk, Lq);
}